// Round 8
// baseline (4572.921 us; speedup 1.0000x reference)
//
#include <hip/hip_runtime.h>
#include <stdint.h>

#define T_DIM 512
#define B_DIM 64
#define E_DIM 1024
#define H_DIM 1024
#define G_DIM 4096   // 4*H, packed as p = j*4 + gate
#define SBLK 256     // scan blocks = CU count (1/CU by LDS, all co-resident)
#define CPB  64      // packed gate-cols per scan block (= 16 hidden units)

typedef short bf16x8 __attribute__((ext_vector_type(8)));
typedef float f32x4 __attribute__((ext_vector_type(4)));

// bf16 -inf: impossible as an h value (h = o*tanh in [-1,1]) -> data sentinel
#define SENT16 0xFF80u
#define SENT64 0xFF80FF80FF80FF80ULL

__device__ __forceinline__ unsigned short f2b(float f){
  union{float f; unsigned u;} v; v.f = f;
  unsigned r = (v.u + 0x7FFFu + ((v.u >> 16) & 1u)) >> 16;  // RNE
  return (unsigned short)r;
}
__device__ __forceinline__ float b2f(unsigned short u){
  union{unsigned u; float f;} v; v.u = ((unsigned)u) << 16; return v.f;
}
__device__ __forceinline__ float fsigmoid(float x){
  return 1.f / (1.f + __expf(-x));
}
__device__ __forceinline__ float ftanh(float x){
  return 2.f / (1.f + __expf(-2.f * x)) - 1.f;
}

// 16B coherent load (sc0 sc1: served at device-coherent point, never a stale
// per-XCD L2 line) — r5/r6/r7-proven for cross-XCD h exchange.
template<int OFF>
__device__ __forceinline__ bf16x8 ld_h16(const unsigned short* p){
  bf16x8 r;
  asm volatile("global_load_dwordx4 %0, %1, off offset:%2 sc0 sc1"
               : "=v"(r) : "v"(p), "i"(OFF) : "memory");
  return r;
}
// plain 16B load (xg: producer kernel boundary already made it visible)
__device__ __forceinline__ bf16x8 ld_g16(const unsigned short* p){
  bf16x8 r;
  asm volatile("global_load_dwordx4 %0, %1, off"
               : "=v"(r) : "v"(p) : "memory");
  return r;
}

// reload the fragments whose mask bit is set (exec-masked 16B loads)
#define RELOAD8(mask, dst, base, K0) \
  if(((mask)>>0)&1u) dst[0]=ld_h16<((K0)+0)*64>(base); \
  if(((mask)>>1)&1u) dst[1]=ld_h16<((K0)+1)*64>(base); \
  if(((mask)>>2)&1u) dst[2]=ld_h16<((K0)+2)*64>(base); \
  if(((mask)>>3)&1u) dst[3]=ld_h16<((K0)+3)*64>(base); \
  if(((mask)>>4)&1u) dst[4]=ld_h16<((K0)+4)*64>(base); \
  if(((mask)>>5)&1u) dst[5]=ld_h16<((K0)+5)*64>(base); \
  if(((mask)>>6)&1u) dst[6]=ld_h16<((K0)+6)*64>(base); \
  if(((mask)>>7)&1u) dst[7]=ld_h16<((K0)+7)*64>(base);

// a 16B fragment spans two 8B producer stores -> check one canary per half
#define CHECK8(mask, dst) { \
  mask = 0; \
  _Pragma("unroll") \
  for (int f_ = 0; f_ < 8; ++f_) \
    mask |= (unsigned)(((unsigned short)dst[f_][0]) == SENT16 || \
                       ((unsigned short)dst[f_][4]) == SENT16) << f_; }

// 8 kc-steps: per kc read 4 B-frags (4 col-tiles) from LDS, 4 MFMAs into
// 4 independent acc chains.
#define MFMA_GRP(buf, G) \
  { _Pragma("unroll") \
    for (int u = 0; u < 8; ++u){ \
      int kc_ = (G)*8 + u; \
      bf16x8 b0 = *(const bf16x8*)&Wl[((0*32 + kc_)*64 + lane)*8]; \
      bf16x8 b1 = *(const bf16x8*)&Wl[((1*32 + kc_)*64 + lane)*8]; \
      bf16x8 b2 = *(const bf16x8*)&Wl[((2*32 + kc_)*64 + lane)*8]; \
      bf16x8 b3 = *(const bf16x8*)&Wl[((3*32 + kc_)*64 + lane)*8]; \
      acc0 = __builtin_amdgcn_mfma_f32_16x16x32_bf16(buf[u], b0, acc0, 0,0,0); \
      acc1 = __builtin_amdgcn_mfma_f32_16x16x32_bf16(buf[u], b1, acc1, 0,0,0); \
      acc2 = __builtin_amdgcn_mfma_f32_16x16x32_bf16(buf[u], b2, acc2, 0,0,0); \
      acc3 = __builtin_amdgcn_mfma_f32_16x16x32_bf16(buf[u], b3, acc3, 0,0,0); \
    } }

// ---------------- prep kernels ----------------

__global__ void pack_weights(const float* __restrict__ Wf, const float* __restrict__ Wi,
                             const float* __restrict__ Wo, const float* __restrict__ Wc,
                             const float* __restrict__ bfv, const float* __restrict__ biv,
                             const float* __restrict__ bov, const float* __restrict__ bcv,
                             unsigned short* __restrict__ WxB, unsigned short* __restrict__ WhB,
                             float* __restrict__ biasP){
  int p = blockIdx.x;            // 0..4095
  int j = p >> 2, g = p & 3;
  const float* W    = (g==0)?Wf:(g==1)?Wi:(g==2)?Wo:Wc;
  const float* bsrc = (g==0)?bfv:(g==1)?biv:(g==2)?bov:bcv;
  const float* wrow = W + (size_t)j * 2048;
  int t = threadIdx.x;           // 256 threads, 4 k each
  float4 x = *(const float4*)(wrow + 4*t);
  float4 h = *(const float4*)(wrow + 1024 + 4*t);
  ushort4 xo = make_ushort4(f2b(x.x), f2b(x.y), f2b(x.z), f2b(x.w));
  ushort4 ho = make_ushort4(f2b(h.x), f2b(h.y), f2b(h.z), f2b(h.w));
  *(ushort4*)&WxB[(size_t)p*1024 + 4*t] = xo;
  *(ushort4*)&WhB[(size_t)p*1024 + 4*t] = ho;
  if (t == 0) biasP[p] = bsrc[j];
}

__global__ void conv_emb(const float* __restrict__ emb, unsigned short* __restrict__ embB,
                         size_t n4){
  for (size_t i = (size_t)blockIdx.x * blockDim.x + threadIdx.x; i < n4;
       i += (size_t)gridDim.x * blockDim.x){
    float4 v = ((const float4*)emb)[i];
    ((ushort4*)embB)[i] = make_ushort4(f2b(v.x), f2b(v.y), f2b(v.z), f2b(v.w));
  }
}

// hbuf: 3 slots of [B][H]. scan mode: slots 0,1 = sentinel, slot 2 = h(-1)=0.
// fallback mode: slots 0,1 = zeros. flags zeroed in both modes.
__global__ void zero_state(unsigned short* __restrict__ hbuf,
                           float* __restrict__ c, int* __restrict__ flags,
                           int scan_mode){
  int i = blockIdx.x * blockDim.x + threadIdx.x;  // 65536 threads exactly
  unsigned short s = scan_mode ? (unsigned short)SENT16 : (unsigned short)0;
  hbuf[i] = s;
  hbuf[i + B_DIM*H_DIM] = s;
  hbuf[i + 2*B_DIM*H_DIM] = 0;
  c[i] = 0.f;
  if (i < SBLK * 16) flags[i] = 0;
}

// ---------------- big GEMM: xg_chunk = embB @ WxB^T (bf16 out) ----------------
__launch_bounds__(256)
__global__ void gemm_xg(const unsigned short* __restrict__ A,
                        const unsigned short* __restrict__ B,
                        unsigned short* __restrict__ C){
  __shared__ unsigned short Al[128*32];
  __shared__ unsigned short Bl[128*32];
  int m0 = blockIdx.x * 128, n0 = blockIdx.y * 128;
  int tid = threadIdx.x, lane = tid & 63, wid = tid >> 6;
  int mblk = (wid >> 1) * 64, nblk = (wid & 1) * 64;
  int rl = lane & 15, kg = lane >> 4;
  f32x4 acc[4][4] = {};

  for (int kk = 0; kk < 1024; kk += 32){
    {
      int c0 = tid, c1 = tid + 256;
      int r = c0 >> 2, g = c0 & 3, s = g ^ ((r >> 1) & 3);
      *(uint4*)&Al[r*32 + s*8] = *(const uint4*)&A[(size_t)(m0 + r)*1024 + kk + g*8];
      *(uint4*)&Bl[r*32 + s*8] = *(const uint4*)&B[(size_t)(n0 + r)*1024 + kk + g*8];
      r = c1 >> 2; g = c1 & 3; s = g ^ ((r >> 1) & 3);
      *(uint4*)&Al[r*32 + s*8] = *(const uint4*)&A[(size_t)(m0 + r)*1024 + kk + g*8];
      *(uint4*)&Bl[r*32 + s*8] = *(const uint4*)&B[(size_t)(n0 + r)*1024 + kk + g*8];
    }
    __syncthreads();
    bf16x8 a[4], b[4];
    #pragma unroll
    for (int mf = 0; mf < 4; ++mf){
      int r = mblk + mf*16 + rl;
      a[mf] = *(const bf16x8*)&Al[r*32 + (kg ^ ((r >> 1) & 3))*8];
    }
    #pragma unroll
    for (int nf = 0; nf < 4; ++nf){
      int r = nblk + nf*16 + rl;
      b[nf] = *(const bf16x8*)&Bl[r*32 + (kg ^ ((r >> 1) & 3))*8];
    }
    #pragma unroll
    for (int mf = 0; mf < 4; ++mf)
      #pragma unroll
      for (int nf = 0; nf < 4; ++nf)
        acc[mf][nf] = __builtin_amdgcn_mfma_f32_16x16x32_bf16(a[mf], b[nf], acc[mf][nf], 0, 0, 0);
    __syncthreads();
  }

  // C/D layout (m89-verified): col = lane&15, row = (lane>>4)*4 + reg
  int rq = kg * 4;
  #pragma unroll
  for (int mf = 0; mf < 4; ++mf)
    #pragma unroll
    for (int nf = 0; nf < 4; ++nf){
      int col = n0 + nblk + nf*16 + rl;
      #pragma unroll
      for (int r = 0; r < 4; ++r){
        int row = m0 + mblk + mf*16 + rq + r;
        C[(size_t)row * G_DIM + col] = f2b(acc[mf][nf][r]);
      }
    }
}

// ---------------- persistent recurrent scan (flags + sentinel hybrid) ----------------
// 256 blocks x 64 threads, 1 block/CU. Block = (cs=blk>>2: 16 hidden units;
// rq=blk&3: 16 batch rows). Wh slice in LDS fragment-major. h: 3-slot rotating
// buffer. Producer: h store -> flag store, back-to-back, NO drain (flag may
// beat data). Consumer: speculative A-load first; if any granule reads the
// sentinel (bf16 -inf, unreachable as real h), spin the 64 same-rq flags in
// parallel, then reload only stale fragments (bounded). Sentinel resets of
// slot (t+1)%3 are issued pre-GEMM and drained by the vmcnt(0) before the h
// store, preserving the r7 ordering proof (reset-visible <= h(t)-visible,
// so slot reads are only {sentinel, h(t-1)}, never h(t-4)).
__launch_bounds__(64, 1)
__global__ void lstm_scan(const unsigned short* __restrict__ WhB,
                          const unsigned short* __restrict__ xgc,  // bf16 [t1-t0][B][G]
                          const float* __restrict__ biasP,
                          unsigned short* __restrict__ hbuf,       // 3 x [B][H]
                          float* __restrict__ cglob,
                          float* __restrict__ out,
                          int* __restrict__ flags,
                          int t0, int t1){
  __shared__ unsigned short Wl[4*32*64*8];   // 128 KB frag-major [ct][kc][lane][8]
  __shared__ float gl[16][68];               // 4.35 KB gate staging (+pad)

  const int tid = threadIdx.x;               // 0..63 (one wave)
  const int blk = blockIdx.x;
  const int cs = blk >> 2, rq = blk & 3;
  const int lane = tid;
  const int rl = lane & 15, kg = lane >> 4;

  // One-time: stage Wh fragments (A/B share the same (lane,elem)->k map)
  for (int idx = tid; idx < 4*32*64; idx += 64){
    int ct = idx >> 11, kc = (idx >> 6) & 31, l = idx & 63;
    int col = cs*CPB + ct*16 + (l & 15);
    int k   = kc*32 + (l >> 4)*8;
    *(bf16x8*)&Wl[idx*8] = *(const bf16x8*)&WhB[(size_t)col*1024 + k];
  }

  // elementwise mapping: thread -> (local batch row bb, 16 packed cols at cb)
  const int bb = tid >> 2, q = tid & 3, cb = q * 16;
  const int rowg = rq*16 + bb;               // global batch row
  const int jb = cs*16 + q*4;                // 4 hidden units owned
  f32x4 bias[4];
  #pragma unroll
  for (int p = 0; p < 4; ++p)
    bias[p] = *(const f32x4*)&biasP[cs*CPB + cb + p*4];
  f32x4 cv = *(const f32x4*)&cglob[(size_t)rowg*H_DIM + jb];

  // lane l polls the flag of same-rq producer block (4l+rq) = col-slice l
  const int* fpoll = &flags[(4*lane + rq) * 16];

  __syncthreads();

  // prologue xg prefetch for t0
  const unsigned short* xgp0 = xgc + ((size_t)0*B_DIM + rowg)*G_DIM + cs*CPB + cb;
  bf16x8 xr0 = ld_g16(xgp0);
  bf16x8 xr1 = ld_g16(xgp0 + 8);

  for (int t = t0; t < t1; ++t){
    const unsigned short* hin  = hbuf + (size_t)((t + 2) % 3) * B_DIM * H_DIM;
    unsigned short*       hout = hbuf + (size_t)( t      % 3) * B_DIM * H_DIM;
    unsigned short*       hrst = hbuf + (size_t)((t + 1) % 3) * B_DIM * H_DIM;

    // --- speculative A load (the load we need anyway) + sentinel verify ---
    const unsigned short* ap = hin + (size_t)(rq*16 + rl)*1024 + kg*8;
    bf16x8 aA[8], aB[8], aC[8], aD[8];
    unsigned mA = 0xFFu, mB = 0xFFu, mC = 0xFFu, mD = 0xFFu;
    RELOAD8(mA, aA, ap, 0);
    RELOAD8(mB, aB, ap, 8);
    RELOAD8(mC, aC, ap, 16);
    RELOAD8(mD, aD, ap, 24);
    asm volatile("s_waitcnt vmcnt(0)" ::: "memory");
    __builtin_amdgcn_sched_barrier(0);
    CHECK8(mA, aA); CHECK8(mB, aB); CHECK8(mC, aC); CHECK8(mD, aD);
    if (__any((mA | mB | mC | mD) != 0u)){
      // slow path: wait for all 64 producer flags (cheap 8B parallel polls),
      // then reload only stale fragments until clean (flag may beat data).
      while (__any(__hip_atomic_load(fpoll, __ATOMIC_RELAXED,
                                     __HIP_MEMORY_SCOPE_AGENT) < t))
        __builtin_amdgcn_s_sleep(1);
      for (int pass = 0; pass < 4096; ++pass){
        RELOAD8(mA, aA, ap, 0);
        RELOAD8(mB, aB, ap, 8);
        RELOAD8(mC, aC, ap, 16);
        RELOAD8(mD, aD, ap, 24);
        asm volatile("s_waitcnt vmcnt(0)" ::: "memory");
        __builtin_amdgcn_sched_barrier(0);
        CHECK8(mA, aA); CHECK8(mB, aB); CHECK8(mC, aC); CHECK8(mD, aD);
        if (!__any((mA | mB | mC | mD) != 0u)) break;
        __builtin_amdgcn_s_sleep(1);
      }
    }

    // verified h(t-1) -> all consumers finished reading h(t-2): reset slot
    // (t+1)%3 (own 16x16 region) to sentinel; drained by vmcnt(0) below.
    __hip_atomic_store(
        (unsigned long long*)&hrst[(size_t)(rq*16 + rl)*H_DIM + cs*16 + kg*4],
        SENT64, __ATOMIC_RELAXED, __HIP_MEMORY_SCOPE_AGENT);

    // --- GEMM: 16 rows x 64 pcols, K=1024, 4 acc chains (B from LDS) ---
    f32x4 acc0 = {}, acc1 = {}, acc2 = {}, acc3 = {};
    MFMA_GRP(aA, 0);
    MFMA_GRP(aB, 1);
    MFMA_GRP(aC, 2);
    MFMA_GRP(aD, 3);

    // scatter to LDS; C/D: col=lane&15, row=(lane>>4)*4+reg (m89-verified)
    {
      int r0 = kg * 4;
      #pragma unroll
      for (int r = 0; r < 4; ++r){
        gl[r0 + r][ 0 + rl] = acc0[r];
        gl[r0 + r][16 + rl] = acc1[r];
        gl[r0 + r][32 + rl] = acc2[r];
        gl[r0 + r][48 + rl] = acc3[r];
      }
    }
    __syncthreads();

    // gates: thread handles 4 hidden units (16 packed cols at cb)
    union { ushort4 s; unsigned long long qq; } hu;
    f32x4 ov;
    {
      f32x4 g0, g1, g2, g3;
      #pragma unroll
      for (int e = 0; e < 4; ++e){
        g0[e] = gl[bb][cb +  0 + e] + b2f(xr0[e])     + bias[0][e];
        g1[e] = gl[bb][cb +  4 + e] + b2f(xr0[4 + e]) + bias[1][e];
        g2[e] = gl[bb][cb +  8 + e] + b2f(xr1[e])     + bias[2][e];
        g3[e] = gl[bb][cb + 12 + e] + b2f(xr1[4 + e]) + bias[3][e];
      }
      float f, i_, o, ct_, hn;
      f = fsigmoid(g0[0]); i_ = fsigmoid(g0[1]); o = fsigmoid(g0[2]); ct_ = ftanh(g0[3]);
      cv[0] = f*cv[0] + i_*ct_; hn = o*ftanh(cv[0]); hu.s.x = f2b(hn); ov[0] = hn;
      f = fsigmoid(g1[0]); i_ = fsigmoid(g1[1]); o = fsigmoid(g1[2]); ct_ = ftanh(g1[3]);
      cv[1] = f*cv[1] + i_*ct_; hn = o*ftanh(cv[1]); hu.s.y = f2b(hn); ov[1] = hn;
      f = fsigmoid(g2[0]); i_ = fsigmoid(g2[1]); o = fsigmoid(g2[2]); ct_ = ftanh(g2[3]);
      cv[2] = f*cv[2] + i_*ct_; hn = o*ftanh(cv[2]); hu.s.z = f2b(hn); ov[2] = hn;
      f = fsigmoid(g3[0]); i_ = fsigmoid(g3[1]); o = fsigmoid(g3[2]); ct_ = ftanh(g3[3]);
      cv[3] = f*cv[3] + i_*ct_; hn = o*ftanh(cv[3]); hu.s.w = f2b(hn); ov[3] = hn;
    }

    // drain the (old, ~free) sentinel reset so reset-visible <= h-visible
    asm volatile("s_waitcnt vmcnt(0)" ::: "memory");
    // publish h(t), then flag — back-to-back, no ack (sentinels repair races)
    __hip_atomic_store((unsigned long long*)&hout[(size_t)rowg*H_DIM + jb], hu.qq,
                       __ATOMIC_RELAXED, __HIP_MEMORY_SCOPE_AGENT);
    if (tid == 0)
      __hip_atomic_store(&flags[blk * 16], t + 1,
                         __ATOMIC_RELAXED, __HIP_MEMORY_SCOPE_AGENT);
    // shadow work (executes under the next step's discovery window)
    *(f32x4*)&out[((size_t)rowg*T_DIM + t)*H_DIM + jb] = ov;
    if (t + 1 < t1){
      const unsigned short* xgp = xgc + ((size_t)(t + 1 - t0)*B_DIM + rowg)*G_DIM + cs*CPB + cb;
      xr0 = ld_g16(xgp);
      xr1 = ld_g16(xgp + 8);
    }
    __syncthreads();
  }

  *(f32x4*)&cglob[(size_t)rowg*H_DIM + jb] = cv;
}

// ---------------- round-1 proven fallback: per-step launched kernel ----------------
__device__ __forceinline__ bf16x8 cvt_f8(const float* p){
  float4 u = *(const float4*)p;
  float4 v = *(const float4*)(p + 4);
  bf16x8 r;
  r[0] = (short)f2b(u.x); r[1] = (short)f2b(u.y); r[2] = (short)f2b(u.z); r[3] = (short)f2b(u.w);
  r[4] = (short)f2b(v.x); r[5] = (short)f2b(v.y); r[6] = (short)f2b(v.z); r[7] = (short)f2b(v.w);
  return r;
}

__launch_bounds__(256)
__global__ void lstm_step(const unsigned short* __restrict__ WhB,
                          const unsigned short* __restrict__ WxB,
                          const float* __restrict__ emb_t,
                          const unsigned short* __restrict__ h_in,
                          unsigned short* __restrict__ h_out,
                          float* __restrict__ cbuf,
                          const float* __restrict__ biasP,
                          float* __restrict__ out, int t){
  __shared__ float glds[64 * 17];
  int tid = threadIdx.x, lane = tid & 63, w = tid >> 6;
  int blk = blockIdx.x;
  int rl = lane & 15, kg = lane >> 4;
  int arow = w * 16 + rl;
  int pcol = blk * 16 + rl;

  f32x4 acc0 = {}, acc1 = {};
  const unsigned short* hrow = h_in + (size_t)arow * 1024 + kg * 8;
  const unsigned short* wrow = WhB + (size_t)pcol * 1024 + kg * 8;
  #pragma unroll 4
  for (int kk = 0; kk < 1024; kk += 64){
    bf16x8 a0 = *(const bf16x8*)(hrow + kk);
    bf16x8 b0 = *(const bf16x8*)(wrow + kk);
    bf16x8 a1 = *(const bf16x8*)(hrow + kk + 32);
    bf16x8 b1 = *(const bf16x8*)(wrow + kk + 32);
    acc0 = __builtin_amdgcn_mfma_f32_16x16x32_bf16(a0, b0, acc0, 0, 0, 0);
    acc1 = __builtin_amdgcn_mfma_f32_16x16x32_bf16(a1, b1, acc1, 0, 0, 0);
  }
  {
    const float* xrow = emb_t + (size_t)arow * 1024 + kg * 8;
    const unsigned short* wxrow = WxB + (size_t)pcol * 1024 + kg * 8;
    #pragma unroll 4
    for (int kk = 0; kk < 1024; kk += 64){
      bf16x8 a0 = cvt_f8(xrow + kk);
      bf16x8 b0 = *(const bf16x8*)(wxrow + kk);
      bf16x8 a1 = cvt_f8(xrow + kk + 32);
      bf16x8 b1 = *(const bf16x8*)(wxrow + kk + 32);
      acc0 = __builtin_amdgcn_mfma_f32_16x16x32_bf16(a0, b0, acc0, 0, 0, 0);
      acc1 = __builtin_amdgcn_mfma_f32_16x16x32_bf16(a1, b1, acc1, 0, 0, 0);
    }
  }
  f32x4 acc = acc0 + acc1;

  #pragma unroll
  for (int r = 0; r < 4; ++r){
    int brow = w * 16 + kg * 4 + r;
    glds[brow * 17 + rl] = acc[r];
  }
  __syncthreads();

  int b = tid >> 2, jj = tid & 3;
  int j = blk * 4 + jj;
  int pbase = blk * 16 + jj * 4;
  float gf = glds[b*17 + jj*4 + 0] + biasP[pbase + 0];
  float gi = glds[b*17 + jj*4 + 1] + biasP[pbase + 1];
  float go = glds[b*17 + jj*4 + 2] + biasP[pbase + 2];
  float gc = glds[b*17 + jj*4 + 3] + biasP[pbase + 3];
  float f  = fsigmoid(gf);
  float i_ = fsigmoid(gi);
  float o  = fsigmoid(go);
  float ct = ftanh(gc);
  float c_old = cbuf[b * H_DIM + j];
  float cn = f * c_old + i_ * ct;
  float hn = o * ftanh(cn);
  cbuf[b * H_DIM + j] = cn;
  h_out[b * H_DIM + j] = f2b(hn);
  out[((size_t)b * T_DIM + t) * H_DIM + j] = hn;
}

// ---------------- launch ----------------
extern "C" void kernel_launch(void* const* d_in, const int* in_sizes, int n_in,
                              void* d_out, int out_size, void* d_ws, size_t ws_size,
                              hipStream_t stream){
  (void)in_sizes; (void)n_in; (void)out_size;
  const float* emb = (const float*)d_in[0];
  const float* Wf  = (const float*)d_in[1];
  const float* bfv = (const float*)d_in[2];
  const float* Wi  = (const float*)d_in[3];
  const float* biv = (const float*)d_in[4];
  const float* Wo  = (const float*)d_in[5];
  const float* bov = (const float*)d_in[6];
  const float* Wc  = (const float*)d_in[7];
  const float* bcv = (const float*)d_in[8];
  float* out = (float*)d_out;

  char* ws = (char*)d_ws;
  size_t off = 0;
  auto alloc = [&](size_t bytes) -> void* {
    void* p = ws + off; off += (bytes + 255) & ~(size_t)255; return p;
  };
  unsigned short* WxB   = (unsigned short*)alloc((size_t)G_DIM * 1024 * 2);
  unsigned short* WhB   = (unsigned short*)alloc((size_t)G_DIM * 1024 * 2);
  float*          biasP = (float*)alloc((size_t)G_DIM * 4);
  unsigned short* hbuf  = (unsigned short*)alloc((size_t)3 * B_DIM * H_DIM * 2);
  float*          cglob = (float*)alloc((size_t)B_DIM * H_DIM * 4);
  int*            flags = (int*)alloc((size_t)SBLK * 16 * 4);
  size_t base_end = off;

  // choose largest T-chunk whose embB(bf16) + xg(bf16) buffers fit in d_ws
  int Tc = 0;
  const int cands[6] = {512, 256, 128, 64, 32, 16};
  for (int ci = 0; ci < 6; ++ci){
    size_t need = base_end
                + (size_t)cands[ci] * B_DIM * E_DIM * 2   // embB chunk
                + (size_t)cands[ci] * B_DIM * G_DIM * 2   // xg chunk (bf16)
                + 4096;
    if (ws_size >= need){ Tc = cands[ci]; break; }
  }
  unsigned short* embB = nullptr;
  unsigned short* xgc  = nullptr;
  if (Tc > 0){
    embB = (unsigned short*)alloc((size_t)Tc * B_DIM * E_DIM * 2);
    xgc  = (unsigned short*)alloc((size_t)Tc * B_DIM * G_DIM * 2);
  }

  pack_weights<<<G_DIM, 256, 0, stream>>>(Wf, Wi, Wo, Wc, bfv, biv, bov, bcv, WxB, WhB, biasP);
  zero_state<<<256, 256, 0, stream>>>(hbuf, cglob, flags, Tc > 0 ? 1 : 0);

  if (Tc > 0){
    for (int t0 = 0; t0 < T_DIM; t0 += Tc){
      conv_emb<<<2048, 256, 0, stream>>>(emb + (size_t)t0 * B_DIM * E_DIM, embB,
                                         (size_t)Tc * B_DIM * E_DIM / 4);
      gemm_xg<<<dim3(Tc * B_DIM / 128, G_DIM / 128), 256, 0, stream>>>(embB, WxB, xgc);
      lstm_scan<<<SBLK, 64, 0, stream>>>(WhB, xgc, biasP, hbuf, cglob, out,
                                         flags, t0, t0 + Tc);
    }
  } else {
    // round-1 proven fallback: fused per-step kernels (no big buffers needed)
    unsigned short* h0 = hbuf;
    unsigned short* h1 = hbuf + (size_t)B_DIM * H_DIM;
    for (int t = 0; t < T_DIM; ++t){
      const unsigned short* hin = (t & 1) ? h1 : h0;
      unsigned short*      hout = (t & 1) ? h0 : h1;
      lstm_step<<<256, 256, 0, stream>>>(
          WhB, WxB, emb + (size_t)t * B_DIM * E_DIM, hin, hout, cglob, biasP, out, t);
    }
  }
}

// Round 9
// 3022.628 us; speedup vs baseline: 1.5129x; 1.5129x over previous
//
#include <hip/hip_runtime.h>
#include <stdint.h>

#define T_DIM 512
#define B_DIM 64
#define E_DIM 1024
#define H_DIM 1024
#define G_DIM 4096   // 4*H, packed as p = j*4 + gate
#define SBLK 256     // scan blocks = CU count (1/CU by LDS, all co-resident)
#define CPB  64      // packed gate-cols per scan block (= 16 hidden units)

typedef short bf16x8 __attribute__((ext_vector_type(8)));
typedef float f32x4 __attribute__((ext_vector_type(4)));

__device__ __forceinline__ unsigned short f2b(float f){
  union{float f; unsigned u;} v; v.f = f;
  unsigned r = (v.u + 0x7FFFu + ((v.u >> 16) & 1u)) >> 16;  // RNE
  return (unsigned short)r;
}
__device__ __forceinline__ float b2f(unsigned short u){
  union{unsigned u; float f;} v; v.u = ((unsigned)u) << 16; return v.f;
}
__device__ __forceinline__ float fsigmoid(float x){
  return 1.f / (1.f + __expf(-x));
}
__device__ __forceinline__ float ftanh(float x){
  return 2.f / (1.f + __expf(-2.f * x)) - 1.f;
}

// 16B coherent load (sc0 sc1: served at device-coherent point, never a stale
// per-XCD L2 line) — r5..r8-proven for cross-XCD h exchange.
template<int OFF>
__device__ __forceinline__ bf16x8 ld_h16(const unsigned short* p){
  bf16x8 r;
  asm volatile("global_load_dwordx4 %0, %1, off offset:%2 sc0 sc1"
               : "=v"(r) : "v"(p), "i"(OFF) : "memory");
  return r;
}
// plain 16B load (xg: producer kernel boundary already made it visible)
__device__ __forceinline__ bf16x8 ld_g16(const unsigned short* p){
  bf16x8 r;
  asm volatile("global_load_dwordx4 %0, %1, off"
               : "=v"(r) : "v"(p) : "memory");
  return r;
}

#define LD8(dst, base, K0) \
  dst[0]=ld_h16<((K0)+0)*64>(base); dst[1]=ld_h16<((K0)+1)*64>(base); \
  dst[2]=ld_h16<((K0)+2)*64>(base); dst[3]=ld_h16<((K0)+3)*64>(base); \
  dst[4]=ld_h16<((K0)+4)*64>(base); dst[5]=ld_h16<((K0)+5)*64>(base); \
  dst[6]=ld_h16<((K0)+6)*64>(base); dst[7]=ld_h16<((K0)+7)*64>(base);

// wait until <=N vmem outstanding; DS_READ (0x100) may hoist past, MFMA/VALU
// may not (rule #18). Counting note: up to 3 "shadow" ops (out store + 2 xg
// prefetch) may be outstanding from the previous step; they are the OLDEST
// ops, so WAITV(24/16/8/0) still guarantees aA/aB/aC/aD completion.
#define WAITV(N) \
  asm volatile("s_waitcnt vmcnt(" #N ")" ::: "memory"); \
  __builtin_amdgcn_sched_barrier(0x100);

// 8 kc-steps: per kc read 4 B-frags (4 col-tiles) from LDS, 4 MFMAs into
// 4 independent acc chains.
#define MFMA_GRP(buf, G) \
  { _Pragma("unroll") \
    for (int u = 0; u < 8; ++u){ \
      int kc_ = (G)*8 + u; \
      bf16x8 b0 = *(const bf16x8*)&Wl[((0*32 + kc_)*64 + lane)*8]; \
      bf16x8 b1 = *(const bf16x8*)&Wl[((1*32 + kc_)*64 + lane)*8]; \
      bf16x8 b2 = *(const bf16x8*)&Wl[((2*32 + kc_)*64 + lane)*8]; \
      bf16x8 b3 = *(const bf16x8*)&Wl[((3*32 + kc_)*64 + lane)*8]; \
      acc0 = __builtin_amdgcn_mfma_f32_16x16x32_bf16(buf[u], b0, acc0, 0,0,0); \
      acc1 = __builtin_amdgcn_mfma_f32_16x16x32_bf16(buf[u], b1, acc1, 0,0,0); \
      acc2 = __builtin_amdgcn_mfma_f32_16x16x32_bf16(buf[u], b2, acc2, 0,0,0); \
      acc3 = __builtin_amdgcn_mfma_f32_16x16x32_bf16(buf[u], b3, acc3, 0,0,0); \
    } }

// ---------------- prep kernels ----------------

__global__ void pack_weights(const float* __restrict__ Wf, const float* __restrict__ Wi,
                             const float* __restrict__ Wo, const float* __restrict__ Wc,
                             const float* __restrict__ bfv, const float* __restrict__ biv,
                             const float* __restrict__ bov, const float* __restrict__ bcv,
                             unsigned short* __restrict__ WxB, unsigned short* __restrict__ WhB,
                             float* __restrict__ biasP){
  int p = blockIdx.x;            // 0..4095
  int j = p >> 2, g = p & 3;
  const float* W    = (g==0)?Wf:(g==1)?Wi:(g==2)?Wo:Wc;
  const float* bsrc = (g==0)?bfv:(g==1)?biv:(g==2)?bov:bcv;
  const float* wrow = W + (size_t)j * 2048;
  int t = threadIdx.x;           // 256 threads, 4 k each
  float4 x = *(const float4*)(wrow + 4*t);
  float4 h = *(const float4*)(wrow + 1024 + 4*t);
  ushort4 xo = make_ushort4(f2b(x.x), f2b(x.y), f2b(x.z), f2b(x.w));
  ushort4 ho = make_ushort4(f2b(h.x), f2b(h.y), f2b(h.z), f2b(h.w));
  *(ushort4*)&WxB[(size_t)p*1024 + 4*t] = xo;
  *(ushort4*)&WhB[(size_t)p*1024 + 4*t] = ho;
  if (t == 0) biasP[p] = bsrc[j];
}

__global__ void conv_emb(const float* __restrict__ emb, unsigned short* __restrict__ embB,
                         size_t n4){
  for (size_t i = (size_t)blockIdx.x * blockDim.x + threadIdx.x; i < n4;
       i += (size_t)gridDim.x * blockDim.x){
    float4 v = ((const float4*)emb)[i];
    ((ushort4*)embB)[i] = make_ushort4(f2b(v.x), f2b(v.y), f2b(v.z), f2b(v.w));
  }
}

__global__ void zero_state(unsigned short* __restrict__ h0, unsigned short* __restrict__ h1,
                           float* __restrict__ c, int* __restrict__ flags){
  int i = blockIdx.x * blockDim.x + threadIdx.x;  // 65536 threads exactly
  h0[i] = 0; h1[i] = 0; c[i] = 0.f;
  if (i < SBLK * 16) flags[i] = 0;
}

// ---------------- big GEMM: xg_chunk = embB @ WxB^T (bf16 out) ----------------
__launch_bounds__(256)
__global__ void gemm_xg(const unsigned short* __restrict__ A,
                        const unsigned short* __restrict__ B,
                        unsigned short* __restrict__ C){
  __shared__ unsigned short Al[128*32];
  __shared__ unsigned short Bl[128*32];
  int m0 = blockIdx.x * 128, n0 = blockIdx.y * 128;
  int tid = threadIdx.x, lane = tid & 63, wid = tid >> 6;
  int mblk = (wid >> 1) * 64, nblk = (wid & 1) * 64;
  int rl = lane & 15, kg = lane >> 4;
  f32x4 acc[4][4] = {};

  for (int kk = 0; kk < 1024; kk += 32){
    {
      int c0 = tid, c1 = tid + 256;
      int r = c0 >> 2, g = c0 & 3, s = g ^ ((r >> 1) & 3);
      *(uint4*)&Al[r*32 + s*8] = *(const uint4*)&A[(size_t)(m0 + r)*1024 + kk + g*8];
      *(uint4*)&Bl[r*32 + s*8] = *(const uint4*)&B[(size_t)(n0 + r)*1024 + kk + g*8];
      r = c1 >> 2; g = c1 & 3; s = g ^ ((r >> 1) & 3);
      *(uint4*)&Al[r*32 + s*8] = *(const uint4*)&A[(size_t)(m0 + r)*1024 + kk + g*8];
      *(uint4*)&Bl[r*32 + s*8] = *(const uint4*)&B[(size_t)(n0 + r)*1024 + kk + g*8];
    }
    __syncthreads();
    bf16x8 a[4], b[4];
    #pragma unroll
    for (int mf = 0; mf < 4; ++mf){
      int r = mblk + mf*16 + rl;
      a[mf] = *(const bf16x8*)&Al[r*32 + (kg ^ ((r >> 1) & 3))*8];
    }
    #pragma unroll
    for (int nf = 0; nf < 4; ++nf){
      int r = nblk + nf*16 + rl;
      b[nf] = *(const bf16x8*)&Bl[r*32 + (kg ^ ((r >> 1) & 3))*8];
    }
    #pragma unroll
    for (int mf = 0; mf < 4; ++mf)
      #pragma unroll
      for (int nf = 0; nf < 4; ++nf)
        acc[mf][nf] = __builtin_amdgcn_mfma_f32_16x16x32_bf16(a[mf], b[nf], acc[mf][nf], 0, 0, 0);
    __syncthreads();
  }

  // C/D layout (m89-verified): col = lane&15, row = (lane>>4)*4 + reg
  int rq = kg * 4;
  #pragma unroll
  for (int mf = 0; mf < 4; ++mf)
    #pragma unroll
    for (int nf = 0; nf < 4; ++nf){
      int col = n0 + nblk + nf*16 + rl;
      #pragma unroll
      for (int r = 0; r < 4; ++r){
        int row = m0 + mblk + mf*16 + rq + r;
        C[(size_t)row * G_DIM + col] = f2b(acc[mf][nf][r]);
      }
    }
}

// ---------------- persistent recurrent scan (r6 flag barrier, lean tail) ----------------
// 256 blocks x 64 threads, 1 block/CU. Block = (cs=blk>>2: 16 hidden units;
// rq=blk&3: 16 batch rows). Wh slice in LDS fragment-major. h in 2-slot
// ping-pong; per-rq flag barrier at END of step (flag t+1 => "stored h(t) AND
// finished reading h(t-1)", so overwriting h(t-1)'s slot at step t+1 is safe;
// h ack'd at coherent point BEFORE flag issues => flag implies h visible).
// r9 change vs r6: pre-flag vmcnt(0) drains ONLY the h store — the out store
// and next-step xg prefetch are issued AFTER the flag and complete in the
// spin's shadow (they are the oldest <=3 outstanding ops at the next step's
// counted WAITV, which remains exact).
__launch_bounds__(64, 1)
__global__ void lstm_scan(const unsigned short* __restrict__ WhB,
                          const unsigned short* __restrict__ xgc,  // bf16 [t1-t0][B][G]
                          const float* __restrict__ biasP,
                          unsigned short* __restrict__ hb0,
                          unsigned short* __restrict__ hb1,
                          float* __restrict__ cglob,
                          float* __restrict__ out,
                          int* __restrict__ flags,
                          int t0, int t1){
  __shared__ unsigned short Wl[4*32*64*8];   // 128 KB frag-major [ct][kc][lane][8]
  __shared__ float gl[16][68];               // 4.35 KB gate staging (+pad)

  const int tid = threadIdx.x;               // 0..63 (one wave)
  const int blk = blockIdx.x;
  const int cs = blk >> 2, rq = blk & 3;
  const int lane = tid;
  const int rl = lane & 15, kg = lane >> 4;

  // One-time: stage Wh fragments (A/B share the same (lane,elem)->k map)
  for (int idx = tid; idx < 4*32*64; idx += 64){
    int ct = idx >> 11, kc = (idx >> 6) & 31, l = idx & 63;
    int col = cs*CPB + ct*16 + (l & 15);
    int k   = kc*32 + (l >> 4)*8;
    *(bf16x8*)&Wl[idx*8] = *(const bf16x8*)&WhB[(size_t)col*1024 + k];
  }

  // elementwise mapping: thread -> (local batch row bb, 16 packed cols at cb)
  const int bb = tid >> 2, q = tid & 3, cb = q * 16;
  const int rowg = rq*16 + bb;               // global batch row
  const int jb = cs*16 + q*4;                // 4 hidden units owned
  f32x4 bias[4];
  #pragma unroll
  for (int p = 0; p < 4; ++p)
    bias[p] = *(const f32x4*)&biasP[cs*CPB + cb + p*4];
  f32x4 cv = *(const f32x4*)&cglob[(size_t)rowg*H_DIM + jb];

  // lane l polls the flag of same-rq producer block (4l+rq) = col-slice l
  const int* fpoll = &flags[(4*lane + rq) * 16];

  __syncthreads();
  asm volatile("s_waitcnt vmcnt(0)" ::: "memory");  // clean vmcnt baseline

  // prologue xg prefetch for t0 (2 outstanding ops entering the loop)
  const unsigned short* xgp0 = xgc + ((size_t)0*B_DIM + rowg)*G_DIM + cs*CPB + cb;
  bf16x8 xr0 = ld_g16(xgp0);
  bf16x8 xr1 = ld_g16(xgp0 + 8);

  for (int t = t0; t < t1; ++t){
    const unsigned short* hin = (t & 1) ? hb1 : hb0;
    unsigned short* hout = (t & 1) ? hb0 : hb1;

    // issue all 32 A-frag loads (rows rq*16..+16, K=1024); <=3 shadow ops
    // (out store + 2 xg) from the previous step are the only older ops.
    const unsigned short* ap = hin + (size_t)(rq*16 + rl)*1024 + kg*8;
    bf16x8 aA[8], aB[8], aC[8], aD[8];
    LD8(aA, ap, 0);  LD8(aB, ap, 8);  LD8(aC, ap, 16);  LD8(aD, ap, 24);

    f32x4 acc0 = {}, acc1 = {}, acc2 = {}, acc3 = {};
    WAITV(24);   // shadow(<=3) + aA complete
    MFMA_GRP(aA, 0);
    WAITV(16);   // + aB complete
    MFMA_GRP(aB, 1);
    WAITV(8);    // + aC complete
    MFMA_GRP(aC, 2);
    WAITV(0);    // everything complete (incl. this step's xr0/xr1)
    MFMA_GRP(aD, 3);

    // scatter to LDS; C/D: col=lane&15, row=(lane>>4)*4+reg (m89-verified)
    {
      int r0 = kg * 4;
      #pragma unroll
      for (int r = 0; r < 4; ++r){
        gl[r0 + r][ 0 + rl] = acc0[r];
        gl[r0 + r][16 + rl] = acc1[r];
        gl[r0 + r][32 + rl] = acc2[r];
        gl[r0 + r][48 + rl] = acc3[r];
      }
    }
    __syncthreads();

    // gates: thread handles 4 hidden units (16 packed cols at cb)
    union { ushort4 s; unsigned long long qq; } hu;
    f32x4 ov;
    {
      f32x4 g0, g1, g2, g3;
      #pragma unroll
      for (int e = 0; e < 4; ++e){
        g0[e] = gl[bb][cb +  0 + e] + b2f(xr0[e])     + bias[0][e];
        g1[e] = gl[bb][cb +  4 + e] + b2f(xr0[4 + e]) + bias[1][e];
        g2[e] = gl[bb][cb +  8 + e] + b2f(xr1[e])     + bias[2][e];
        g3[e] = gl[bb][cb + 12 + e] + b2f(xr1[4 + e]) + bias[3][e];
      }
      float f, i_, o, ct_, hn;
      f = fsigmoid(g0[0]); i_ = fsigmoid(g0[1]); o = fsigmoid(g0[2]); ct_ = ftanh(g0[3]);
      cv[0] = f*cv[0] + i_*ct_; hn = o*ftanh(cv[0]); hu.s.x = f2b(hn); ov[0] = hn;
      f = fsigmoid(g1[0]); i_ = fsigmoid(g1[1]); o = fsigmoid(g1[2]); ct_ = ftanh(g1[3]);
      cv[1] = f*cv[1] + i_*ct_; hn = o*ftanh(cv[1]); hu.s.y = f2b(hn); ov[1] = hn;
      f = fsigmoid(g2[0]); i_ = fsigmoid(g2[1]); o = fsigmoid(g2[2]); ct_ = ftanh(g2[3]);
      cv[2] = f*cv[2] + i_*ct_; hn = o*ftanh(cv[2]); hu.s.z = f2b(hn); ov[2] = hn;
      f = fsigmoid(g3[0]); i_ = fsigmoid(g3[1]); o = fsigmoid(g3[2]); ct_ = ftanh(g3[3]);
      cv[3] = f*cv[3] + i_*ct_; hn = o*ftanh(cv[3]); hu.s.w = f2b(hn); ov[3] = hn;
    }

    // publish h(t) at the coherent point
    __hip_atomic_store((unsigned long long*)&hout[(size_t)rowg*H_DIM + jb], hu.qq,
                       __ATOMIC_RELAXED, __HIP_MEMORY_SCOPE_AGENT);

    if (t + 1 < t1){
      // drain ONLY the h store (shadow ops from last step long since done),
      // so flag-visible => h-visible at the coherent point.
      asm volatile("s_waitcnt vmcnt(0)" ::: "memory");
      __syncthreads();
      if (tid == 0)
        __hip_atomic_store(&flags[blk * 16], t + 1,
                           __ATOMIC_RELAXED, __HIP_MEMORY_SCOPE_AGENT);
      // shadow work: executes during the spin; these are the <=3 oldest
      // outstanding ops at the next step's counted WAITV.
      *(f32x4*)&out[((size_t)rowg*T_DIM + t)*H_DIM + jb] = ov;
      {
        const unsigned short* xgp = xgc + ((size_t)(t + 1 - t0)*B_DIM + rowg)*G_DIM + cs*CPB + cb;
        xr0 = ld_g16(xgp);
        xr1 = ld_g16(xgp + 8);
      }
      const int target = t + 1;
      while (__hip_atomic_load(fpoll, __ATOMIC_RELAXED, __HIP_MEMORY_SCOPE_AGENT) < target)
        __builtin_amdgcn_s_sleep(1);
      __syncthreads();
      asm volatile("" ::: "memory");  // keep next-step loads below the spin
    } else {
      // final step: no barrier needed; kernel end drains the out store
      *(f32x4*)&out[((size_t)rowg*T_DIM + t)*H_DIM + jb] = ov;
    }
  }

  *(f32x4*)&cglob[(size_t)rowg*H_DIM + jb] = cv;
}

// ---------------- round-1 proven fallback: per-step launched kernel ----------------
__device__ __forceinline__ bf16x8 cvt_f8(const float* p){
  float4 u = *(const float4*)p;
  float4 v = *(const float4*)(p + 4);
  bf16x8 r;
  r[0] = (short)f2b(u.x); r[1] = (short)f2b(u.y); r[2] = (short)f2b(u.z); r[3] = (short)f2b(u.w);
  r[4] = (short)f2b(v.x); r[5] = (short)f2b(v.y); r[6] = (short)f2b(v.z); r[7] = (short)f2b(v.w);
  return r;
}

__launch_bounds__(256)
__global__ void lstm_step(const unsigned short* __restrict__ WhB,
                          const unsigned short* __restrict__ WxB,
                          const float* __restrict__ emb_t,
                          const unsigned short* __restrict__ h_in,
                          unsigned short* __restrict__ h_out,
                          float* __restrict__ cbuf,
                          const float* __restrict__ biasP,
                          float* __restrict__ out, int t){
  __shared__ float glds[64 * 17];
  int tid = threadIdx.x, lane = tid & 63, w = tid >> 6;
  int blk = blockIdx.x;
  int rl = lane & 15, kg = lane >> 4;
  int arow = w * 16 + rl;
  int pcol = blk * 16 + rl;

  f32x4 acc0 = {}, acc1 = {};
  const unsigned short* hrow = h_in + (size_t)arow * 1024 + kg * 8;
  const unsigned short* wrow = WhB + (size_t)pcol * 1024 + kg * 8;
  #pragma unroll 4
  for (int kk = 0; kk < 1024; kk += 64){
    bf16x8 a0 = *(const bf16x8*)(hrow + kk);
    bf16x8 b0 = *(const bf16x8*)(wrow + kk);
    bf16x8 a1 = *(const bf16x8*)(hrow + kk + 32);
    bf16x8 b1 = *(const bf16x8*)(wrow + kk + 32);
    acc0 = __builtin_amdgcn_mfma_f32_16x16x32_bf16(a0, b0, acc0, 0, 0, 0);
    acc1 = __builtin_amdgcn_mfma_f32_16x16x32_bf16(a1, b1, acc1, 0, 0, 0);
  }
  {
    const float* xrow = emb_t + (size_t)arow * 1024 + kg * 8;
    const unsigned short* wxrow = WxB + (size_t)pcol * 1024 + kg * 8;
    #pragma unroll 4
    for (int kk = 0; kk < 1024; kk += 64){
      bf16x8 a0 = cvt_f8(xrow + kk);
      bf16x8 b0 = *(const bf16x8*)(wxrow + kk);
      bf16x8 a1 = cvt_f8(xrow + kk + 32);
      bf16x8 b1 = *(const bf16x8*)(wxrow + kk + 32);
      acc0 = __builtin_amdgcn_mfma_f32_16x16x32_bf16(a0, b0, acc0, 0, 0, 0);
      acc1 = __builtin_amdgcn_mfma_f32_16x16x32_bf16(a1, b1, acc1, 0, 0, 0);
    }
  }
  f32x4 acc = acc0 + acc1;

  #pragma unroll
  for (int r = 0; r < 4; ++r){
    int brow = w * 16 + kg * 4 + r;
    glds[brow * 17 + rl] = acc[r];
  }
  __syncthreads();

  int b = tid >> 2, jj = tid & 3;
  int j = blk * 4 + jj;
  int pbase = blk * 16 + jj * 4;
  float gf = glds[b*17 + jj*4 + 0] + biasP[pbase + 0];
  float gi = glds[b*17 + jj*4 + 1] + biasP[pbase + 1];
  float go = glds[b*17 + jj*4 + 2] + biasP[pbase + 2];
  float gc = glds[b*17 + jj*4 + 3] + biasP[pbase + 3];
  float f  = fsigmoid(gf);
  float i_ = fsigmoid(gi);
  float o  = fsigmoid(go);
  float ct = ftanh(gc);
  float c_old = cbuf[b * H_DIM + j];
  float cn = f * c_old + i_ * ct;
  float hn = o * ftanh(cn);
  cbuf[b * H_DIM + j] = cn;
  h_out[b * H_DIM + j] = f2b(hn);
  out[((size_t)b * T_DIM + t) * H_DIM + j] = hn;
}

// ---------------- launch ----------------
extern "C" void kernel_launch(void* const* d_in, const int* in_sizes, int n_in,
                              void* d_out, int out_size, void* d_ws, size_t ws_size,
                              hipStream_t stream){
  (void)in_sizes; (void)n_in; (void)out_size;
  const float* emb = (const float*)d_in[0];
  const float* Wf  = (const float*)d_in[1];
  const float* bfv = (const float*)d_in[2];
  const float* Wi  = (const float*)d_in[3];
  const float* biv = (const float*)d_in[4];
  const float* Wo  = (const float*)d_in[5];
  const float* bov = (const float*)d_in[6];
  const float* Wc  = (const float*)d_in[7];
  const float* bcv = (const float*)d_in[8];
  float* out = (float*)d_out;

  char* ws = (char*)d_ws;
  size_t off = 0;
  auto alloc = [&](size_t bytes) -> void* {
    void* p = ws + off; off += (bytes + 255) & ~(size_t)255; return p;
  };
  unsigned short* WxB   = (unsigned short*)alloc((size_t)G_DIM * 1024 * 2);
  unsigned short* WhB   = (unsigned short*)alloc((size_t)G_DIM * 1024 * 2);
  float*          biasP = (float*)alloc((size_t)G_DIM * 4);
  unsigned short* h0    = (unsigned short*)alloc((size_t)B_DIM * H_DIM * 2);
  unsigned short* h1    = (unsigned short*)alloc((size_t)B_DIM * H_DIM * 2);
  float*          cglob = (float*)alloc((size_t)B_DIM * H_DIM * 4);
  int*            flags = (int*)alloc((size_t)SBLK * 16 * 4);
  size_t base_end = off;

  // choose largest T-chunk whose embB(bf16) + xg(bf16) buffers fit in d_ws
  int Tc = 0;
  const int cands[6] = {512, 256, 128, 64, 32, 16};
  for (int ci = 0; ci < 6; ++ci){
    size_t need = base_end
                + (size_t)cands[ci] * B_DIM * E_DIM * 2   // embB chunk
                + (size_t)cands[ci] * B_DIM * G_DIM * 2   // xg chunk (bf16)
                + 4096;
    if (ws_size >= need){ Tc = cands[ci]; break; }
  }
  unsigned short* embB = nullptr;
  unsigned short* xgc  = nullptr;
  if (Tc > 0){
    embB = (unsigned short*)alloc((size_t)Tc * B_DIM * E_DIM * 2);
    xgc  = (unsigned short*)alloc((size_t)Tc * B_DIM * G_DIM * 2);
  }

  pack_weights<<<G_DIM, 256, 0, stream>>>(Wf, Wi, Wo, Wc, bfv, biv, bov, bcv, WxB, WhB, biasP);
  zero_state<<<256, 256, 0, stream>>>(h0, h1, cglob, flags);

  if (Tc > 0){
    for (int t0 = 0; t0 < T_DIM; t0 += Tc){
      conv_emb<<<2048, 256, 0, stream>>>(emb + (size_t)t0 * B_DIM * E_DIM, embB,
                                         (size_t)Tc * B_DIM * E_DIM / 4);
      gemm_xg<<<dim3(Tc * B_DIM / 128, G_DIM / 128), 256, 0, stream>>>(embB, WxB, xgc);
      lstm_scan<<<SBLK, 64, 0, stream>>>(WhB, xgc, biasP, h0, h1, cglob, out,
                                         flags, t0, t0 + Tc);
    }
  } else {
    // round-1 proven fallback: fused per-step kernels (no big buffers needed)
    for (int t = 0; t < T_DIM; ++t){
      const unsigned short* hin = (t & 1) ? h1 : h0;
      unsigned short*      hout = (t & 1) ? h0 : h1;
      lstm_step<<<256, 256, 0, stream>>>(
          WhB, WxB, emb + (size_t)t * B_DIM * E_DIM, hin, hout, cglob, biasP, out, t);
    }
  }
}